// Round 6
// baseline (466.882 us; speedup 1.0000x reference)
//
#include <hip/hip_runtime.h>

#define N_ROWS 262144
#define DIM 64
#define KCODES 512
#define THREADS 512
#define BLK_ROWS 128                       // 8 waves x 16 rows
#define NBLOCKS (N_ROWS / BLK_ROWS)        // 2048
#define CHUNK 128                          // codes staged in LDS per pass
#define NCHUNK (KCODES / CHUNK)            // 4
#define NPART 64                           // partial histograms / sse slots (contention spread)
// error budget: np-e rounding (<=ulp(128)*2 ~3.0e-5) + biased-key quant (3.05e-5)
// + 3-pass bf16 (~2e-6) + flag-gap quantum (3.05e-5) ~= 9.4e-5 < MARGIN_T
#define MARGIN_T 1.25e-4f

// d_out is FLOAT32. Flat layout in return order:
// [0] loss | [1 .. 1+N*D) quantized | [1+N*D] norm_perplexity | [2+N*D ..) indices
#define OFF_Q 1
#define OFF_PERP (1 + (size_t)N_ROWS * DIM)
#define OFF_IDX (2 + (size_t)N_ROWS * DIM)

typedef __attribute__((ext_vector_type(8))) short bf16x8;
typedef __attribute__((ext_vector_type(4))) float f32x4;

// ---------- numerics helpers (numpy-exact machinery, carried over) ----------

// numpy pairwise sum of squares for n=64 (loops.c.src): 8 strided accumulators,
// sequential adds, fixed combine tree. contract(off): square rounds BEFORE add.
__device__ __forceinline__ float np_sum_sq64(const float* __restrict__ v) {
#pragma clang fp contract(off)
    float r[8];
#pragma unroll
    for (int l = 0; l < 8; ++l) r[l] = v[l] * v[l];
#pragma unroll
    for (int k = 1; k < 8; ++k) {
#pragma unroll
        for (int l = 0; l < 8; ++l) {
            float sq = v[8 * k + l] * v[8 * k + l];
            r[l] = r[l] + sq;
        }
    }
    return ((r[0] + r[1]) + (r[2] + r[3])) + ((r[4] + r[5]) + (r[6] + r[7]));
}

// fp32 -> bf16 bits, round-to-nearest-even
__device__ __forceinline__ unsigned short f2bf(float f) {
    unsigned u = __float_as_uint(f);
    u += 0x7FFFu + ((u >> 16) & 1u);
    return (unsigned short)(u >> 16);
}
__device__ __forceinline__ float bf2f(unsigned short h) {
    return __uint_as_float((unsigned)h << 16);
}

// biased sortable key: t in (-0.5, 0.5) guaranteed (|t| <= B + 2|x.w| <= 0.38
// hard bound), so t+0.5 is a positive float -> IEEE bits are order-isomorphic.
// Low 9 mantissa bits replaced by code idx (first-index tie-break for free).
// Quantization <= 511*ulp(0.86) ~= 3.05e-5, covered by MARGIN_T.
__device__ __forceinline__ unsigned t2key(float t, unsigned idx) {
    return (__float_as_uint(t + 0.5f) & 0xFFFFFE00u) | idx;   // v_add + v_and_or
}
__device__ __forceinline__ float key2t(unsigned key) {
    // (t+0.5) in [0.25,1) -> subtracting 0.5 is exact (Sterbenz)
    return __uint_as_float(key & 0xFFFFFE00u) - 0.5f;
}

// ---------- prep: W_hi/W_lo (bf16 of -2W, split) + numpy ||w||^2 ----------

__global__ __launch_bounds__(256) void vq_prep(const float* __restrict__ W,
        unsigned short* __restrict__ WhiG, unsigned short* __restrict__ WloG,
        float* __restrict__ Bsc) {
    int c = blockIdx.x * 256 + threadIdx.x;
    if (c >= KCODES) return;
    const float* w = W + (size_t)c * DIM;
    Bsc[c] = np_sum_sq64(w);                 // numpy summation order
#pragma unroll 4
    for (int d = 0; d < DIM; ++d) {
        float v = -2.0f * w[d];              // exact scale
        unsigned short hi = f2bf(v);
        unsigned short lo = f2bf(v - bf2f(hi));   // split residual, exact subtract
        WhiG[c * DIM + d] = hi;
        WloG[c * DIM + d] = lo;
    }
}

// ---------- main: MFMA distance + packed-key min1/min2 argmin + SSE + hist ----------
// Wave w owns rows [16w,16w+16). MFMA 16x16x32_bf16: A = -2W (M=codes),
// B = X (N=rows), C-init = B_j. 3 passes: ah*xh + ah*xl + al*xh.
// D layout (m89-verified): col=lane&15 (row n), row=(lane>>4)*4+reg (code m).
// SSE_row = ||x||^2 + t1 (unflagged rows); flagged rows go to the global list.

__global__ __launch_bounds__(THREADS, 4) void vq_argmin(
    const float* __restrict__ X,
    const unsigned short* __restrict__ WhiG,
    const unsigned short* __restrict__ WloG,
    const float* __restrict__ Bsc,
    float* __restrict__ out,
    double* __restrict__ sseAcc,
    unsigned* __restrict__ gHistP,
    int* __restrict__ flagList,
    unsigned* __restrict__ gCnt) {

    __shared__ __align__(16) unsigned short sHi[CHUNK * DIM];  // 16 KiB, swizzled
    __shared__ __align__(16) unsigned short sLo[CHUNK * DIM];  // 16 KiB, swizzled
    __shared__ __align__(16) float sX[BLK_ROWS * DIM];         // 32 KiB, swizzled
    __shared__ __align__(16) float sB[KCODES];                 // 2 KiB
    __shared__ unsigned sHist[KCODES];                         // 2 KiB
    __shared__ int sFlagRows[BLK_ROWS];
    __shared__ unsigned sCnt, sBase;
    __shared__ double sSseW[8];

    const int tid = threadIdx.x;
    const int w = tid >> 6;          // wave 0..7
    const int l = tid & 63;          // lane
    const int q = l >> 4;            // lane quad 0..3
    const int r16 = l & 15;          // n / m sub-index
    const int R0 = blockIdx.x * BLK_ROWS;

    // ---- stage X tile (coalesced load, XOR-swizzled store: byte ^= (r&7)<<5) ----
    {
        const float4* g = (const float4*)(X + (size_t)R0 * DIM);
        char* base = (char*)sX;
#pragma unroll
        for (int i = 0; i < (BLK_ROWS * DIM / 4) / THREADS; ++i) {   // 4
            int fidx = tid + THREADS * i;                            // [0,2048)
            int r = fidx >> 4, c4 = fidx & 15;
            int off = (r * 256 + c4 * 16) ^ ((r & 7) << 5);
            *(float4*)(base + off) = g[fidx];
        }
        sB[tid] = Bsc[tid];   // THREADS == KCODES
        sHist[tid] = 0u;
        if (tid == 0) sCnt = 0u;
    }
    __syncthreads();

    // ---- per-lane X fragments: row r = 16w + (l&15), k = 32h + 8q + j ----
    // asum = lane's partial ||x||^2 over its 16 covered dims.
    bf16x8 xh[2], xl[2];
    float asum = 0.f;
    {
        const int r = w * 16 + r16;
        const char* base = (const char*)sX;
#pragma unroll
        for (int h = 0; h < 2; ++h) {
            int b0 = (r * 256 + h * 128 + q * 32) ^ ((r & 7) << 5);
            float4 fa = *(const float4*)(base + b0);
            float4 fb = *(const float4*)(base + b0 + 16);   // bit4 untouched by swizzle
            float f[8] = {fa.x, fa.y, fa.z, fa.w, fb.x, fb.y, fb.z, fb.w};
            bf16x8 hi8, lo8;
#pragma unroll
            for (int j = 0; j < 8; ++j) {
                asum = fmaf(f[j], f[j], asum);
                unsigned short hi = f2bf(f[j]);
                unsigned short lo = f2bf(f[j] - bf2f(hi));
                hi8[j] = (short)hi; lo8[j] = (short)lo;
            }
            xh[h] = hi8; xl[h] = lo8;
        }
    }

    unsigned min1 = 0xFFFFFFFFu, min2 = 0xFFFFFFFFu;

    for (int cc = 0; cc < NCHUNK; ++cc) {
        const int c0 = cc * CHUNK;
        __syncthreads();
        {   // stage -2W chunk hi+lo (coalesced uint4, swizzle: byte ^= (c&7)<<4)
            const uint4* gh = (const uint4*)(WhiG + (size_t)c0 * DIM);
            const uint4* gl = (const uint4*)(WloG + (size_t)c0 * DIM);
            char* bh = (char*)sHi; char* bl = (char*)sLo;
#pragma unroll
            for (int i = 0; i < (CHUNK * DIM / 8) / THREADS; ++i) {  // 2
                int idx = tid + THREADS * i;                          // uint4 idx
                int c = idx >> 3, k8 = idx & 7;
                int off = (c * 128 + k8 * 16) ^ ((c & 7) << 4);
                *(uint4*)(bh + off) = gh[idx];
                *(uint4*)(bl + off) = gl[idx];
            }
        }
        __syncthreads();

#pragma unroll
        for (int ct = 0; ct < CHUNK / 16; ++ct) {
            const int cloc = ct * 16 + r16;     // chunk-local code row of A frag
            const char* bh = (const char*)sHi;
            const char* bl = (const char*)sLo;
            const int sw = (cloc & 7) << 4;
            int o0 = (cloc * 128 + 16 * q) ^ sw;          // k-half 0
            int o1 = (cloc * 128 + 64 + 16 * q) ^ sw;     // k-half 1
            bf16x8 ah0 = *(const bf16x8*)(bh + o0);
            bf16x8 ah1 = *(const bf16x8*)(bh + o1);
            bf16x8 al0 = *(const bf16x8*)(bl + o0);
            bf16x8 al1 = *(const bf16x8*)(bl + o1);

            // C-init = B_j for this lane's 4 codes -> acc ends as t = B - 2*dot
            f32x4 acc = *(const f32x4*)&sB[c0 + ct * 16 + q * 4];

            acc = __builtin_amdgcn_mfma_f32_16x16x32_bf16(ah0, xh[0], acc, 0, 0, 0);
            acc = __builtin_amdgcn_mfma_f32_16x16x32_bf16(ah1, xh[1], acc, 0, 0, 0);
            acc = __builtin_amdgcn_mfma_f32_16x16x32_bf16(ah0, xl[0], acc, 0, 0, 0);
            acc = __builtin_amdgcn_mfma_f32_16x16x32_bf16(ah1, xl[1], acc, 0, 0, 0);
            acc = __builtin_amdgcn_mfma_f32_16x16x32_bf16(al0, xh[0], acc, 0, 0, 0);
            acc = __builtin_amdgcn_mfma_f32_16x16x32_bf16(al1, xh[1], acc, 0, 0, 0);

            // biased-key pack (2 VALU each) + min/max tournament: top-2 of
            // {min1,min2,k0..k3} in 12 ops (vs 4x sequential insert = 28).
            const unsigned jbase = (unsigned)(c0 + ct * 16 + q * 4);
            unsigned k0 = t2key(acc[0], jbase + 0u);
            unsigned k1 = t2key(acc[1], jbase + 1u);
            unsigned k2 = t2key(acc[2], jbase + 2u);
            unsigned k3 = t2key(acc[3], jbase + 3u);
            unsigned lo01 = k0 < k1 ? k0 : k1, hi01 = k0 < k1 ? k1 : k0;
            unsigned lo23 = k2 < k3 ? k2 : k3, hi23 = k2 < k3 ? k3 : k2;
            unsigned m1 = lo01 < lo23 ? lo01 : lo23;     // min of 4
            unsigned mm = lo01 < lo23 ? lo23 : lo01;     // max of the two lows
            unsigned hh = hi01 < hi23 ? hi01 : hi23;     // min of the two highs
            unsigned m2 = hh < mm ? hh : mm;             // 2nd-min of 4
            unsigned nm = min1 < m1 ? m1 : min1;         // max(firsts)
            min1 = min1 < m1 ? min1 : m1;
            unsigned sm = min2 < m2 ? min2 : m2;         // min(seconds)
            min2 = sm < nm ? sm : nm;
        }
    }

    // ---- merge the 4 lane-subsets of each row (lanes l, l^16, l^32, l^48) ----
    // Also merges the 4 partial ||x||^2 sums into the full per-row A.
#pragma unroll
    for (int d = 16; d <= 32; d <<= 1) {
        unsigned o1 = (unsigned)__shfl_xor((int)min1, d, 64);
        unsigned o2 = (unsigned)__shfl_xor((int)min2, d, 64);
        asum += __shfl_xor(asum, d, 64);
        unsigned n1 = min1 < o1 ? min1 : o1;
        unsigned mx = min1 > o1 ? min1 : o1;
        unsigned mn = min2 < o2 ? min2 : o2;
        unsigned n2 = mx < mn ? mx : mn;
        min1 = n1; min2 = n2;
    }

    const unsigned best = min1 & 511u;
    const float t1 = key2t(min1), t2 = key2t(min2);
    const bool flagged = (t2 < t1 + MARGIN_T);

    float ssev = 0.f;
    if (q == 0) {   // row owner: lanes 0..15 -> 16 consecutive rows, coalesced
        const int row = R0 + w * 16 + r16;
        out[OFF_IDX + row] = (float)best;    // flagged rows corrected by fixup
        if (!flagged) {
            ssev = asum + t1;                 // SSE = ||x||^2 + (B - 2*dot)
            atomicAdd(&sHist[best], 1u);
        } else {
            unsigned s = atomicAdd(&sCnt, 1u);
            sFlagRows[s] = row;
        }
    }
    // per-wave SSE reduce (owners hold nonzero), then block-level flush
#pragma unroll
    for (int off = 32; off; off >>= 1) ssev += __shfl_down(ssev, off);
    if (l == 0) sSseW[w] = (double)ssev;
    __syncthreads();

    if (tid == 0) sBase = atomicAdd(gCnt, sCnt);   // global list segment
    {   // flush histogram to partial hist (spreads atomic contention 64x)
        unsigned c = sHist[tid];
        if (c) atomicAdd(&gHistP[(blockIdx.x & (NPART - 1)) * KCODES + tid], c);
    }
    __syncthreads();
    if (tid < (int)sCnt) flagList[sBase + tid] = sFlagRows[tid];
    if (tid == 0) {
        double s = 0.0;
#pragma unroll
        for (int i = 0; i < 8; ++i) s += sSseW[i];
        atomicAdd(sseAcc, s);                 // one fp64 atomic per block (2048 total)
    }
}

// ---------- fixup: exact numpy-fp32 argmin over ALL 512 codes, listed rows ----------
// Grid-stride over the globally-compacted flag list, one 512-thread block per
// row, ONE CODE PER THREAD. The X row lives in REGISTERS (xr[64], all indices
// compile-time): rounds 2/4/5 all stalled ~150-190us on a volatile-LDS /
// barrier-tree x-path (~128 ordered ds_reads x ~120cyc latency per row).
// One W-stream per thread (#pragma unroll 4 bounds load-hoisting) keeps VGPR
// ~110; __launch_bounds__(512,4) caps at 128 (round-3 spill was 4 W-streams +
// xr). X loads are wave-broadcast (same 256B line). Per-code fp64 fma order is
// bit-identical to numpy. u64-key reduce: wave shfl + LDS cross-wave,
// first-index tie-break. Contributes SSE (= exact e) + histogram.

__global__ __launch_bounds__(512, 4) void vq_fixup(
    const float* __restrict__ X, const float* __restrict__ W,
    const float* __restrict__ Bsc, float* __restrict__ out,
    double* __restrict__ sseP, unsigned* __restrict__ gHistP,
    const int* __restrict__ flagList, const unsigned* __restrict__ gCnt) {
    __shared__ unsigned long long sKeyW[8];
    const unsigned total = *gCnt;
    const int t = threadIdx.x;               // == code id
    const int wv = t >> 6, l = t & 63;

    for (unsigned i = blockIdx.x; i < total; i += gridDim.x) {
        const int row = flagList[i];

        float xr[DIM];                       // full row in registers
        {
            const float4* Xr4 = (const float4*)(X + (size_t)row * DIM);
#pragma unroll
            for (int k4 = 0; k4 < 16; ++k4) {
                float4 v = Xr4[k4];
                xr[4 * k4 + 0] = v.x; xr[4 * k4 + 1] = v.y;
                xr[4 * k4 + 2] = v.z; xr[4 * k4 + 3] = v.w;
            }
        }
        const float A = np_sum_sq64(xr);     // numpy order, identical bits all threads

        // exact np_e for code t: fp64 dot in numpy's sequential order
        double acc = 0.0;
        {
            const float4* wr = (const float4*)(W + (size_t)t * DIM);
#pragma unroll 4
            for (int k4 = 0; k4 < 16; ++k4) {
                float4 f = wr[k4];
                acc = fma((double)f.x, (double)xr[4 * k4 + 0], acc);
                acc = fma((double)f.y, (double)xr[4 * k4 + 1], acc);
                acc = fma((double)f.z, (double)xr[4 * k4 + 2], acc);
                acc = fma((double)f.w, (double)xr[4 * k4 + 3], acc);
            }
        }
        unsigned long long bk;
        {
#pragma clang fp contract(off)
            float C2 = (float)(2.0 * acc);
            float e = (A + Bsc[t]) - C2;     // np fp32: (A+B) then subtract
            int iu = __float_as_int(e);
            unsigned u = ((unsigned)iu) ^ (((unsigned)(iu >> 31)) | 0x80000000u);
            bk = ((unsigned long long)u << 32) | (unsigned)t;
        }
#pragma unroll
        for (int d = 1; d < 64; d <<= 1) {
            unsigned long long o =
                (unsigned long long)__shfl_xor((long long)bk, d, 64);
            bk = bk < o ? bk : o;
        }
        if (l == 0) sKeyW[wv] = bk;
        __syncthreads();
        if (t == 0) {
            unsigned long long b = sKeyW[0];
#pragma unroll
            for (int k = 1; k < 8; ++k) if (sKeyW[k] < b) b = sKeyW[k];
            unsigned bestc = (unsigned)(b & 511ULL);
            unsigned u = (unsigned)(b >> 32);
            unsigned fb = (u & 0x80000000u) ? (u & 0x7FFFFFFFu) : ~u;
            float ebest = __uint_as_float(fb);   // exact np-fp32 e of the winner
            out[OFF_IDX + row] = (float)bestc;
            atomicAdd(&gHistP[(i & (NPART - 1)) * KCODES + bestc], 1u);
            atomicAdd(&sseP[i & (NPART - 1)], (double)ebest);   // SSE = e
        }
        __syncthreads();                     // protect sKeyW before next iter
    }
}

// ---------- scatter: pure gather W[best] -> Q (no atomics, no X read) ----------
// One wave per row. Index load is wave-uniform, W gather is one coalesced
// 256B read (L2-hot), store coalesced. Runs on FINAL indices (post-fixup).

__global__ __launch_bounds__(256) void vq_scatter(
    const float* __restrict__ W, float* __restrict__ out) {
    const int gid = blockIdx.x * 256 + threadIdx.x;
    const int row = gid >> 6;
    const int lane = gid & 63;
    int idx = (int)out[OFF_IDX + row];
    if ((unsigned)idx >= KCODES) idx = KCODES - 1;   // safety clamp
    out[OFF_Q + (size_t)row * DIM + lane] = W[(size_t)idx * DIM + lane];
}

// ---------- finalize: sum partial hists -> perplexity; sse -> loss ----------

__global__ __launch_bounds__(512) void vq_finalize(
    const double* __restrict__ sseAcc, const double* __restrict__ sseP,
    const unsigned* __restrict__ gHistP, float* __restrict__ out) {
    __shared__ float partial[8];
    const int t = threadIdx.x;
    unsigned c = 0;
#pragma unroll 8
    for (int p = 0; p < NPART; ++p) c += gHistP[p * KCODES + t];
    float pf = (float)c * (1.0f / (float)N_ROWS);
    float v = pf * logf(pf + 1e-10f);
#pragma unroll
    for (int off = 32; off; off >>= 1) v += __shfl_down(v, off);
    if ((t & 63) == 0) partial[t >> 6] = v;
    __syncthreads();
    if (t == 0) {
        float s = 0.f;
#pragma unroll
        for (int i = 0; i < 8; ++i) s += partial[i];
        out[OFF_PERP] = expf(-s) * (1.0f / (float)KCODES);
        double s2 = sseAcc[0];
#pragma unroll
        for (int i = 0; i < NPART; ++i) s2 += sseP[i];
        out[0] = (float)(1.25 * s2 * (1.0 / ((double)N_ROWS * (double)DIM)));
    }
}

extern "C" void kernel_launch(void* const* d_in, const int* in_sizes, int n_in,
                              void* d_out, int out_size, void* d_ws, size_t ws_size,
                              hipStream_t stream) {
    const float* X = (const float*)d_in[0];
    const float* W = (const float*)d_in[1];
    float* out = (float*)d_out;
    double* sseAcc = (double*)d_ws;
    double* sseP = (double*)((char*)d_ws + 64);       // 64 slots
    unsigned* gCnt = (unsigned*)((char*)d_ws + 64 + NPART * sizeof(double));

    size_t zb = 64 + NPART * sizeof(double) + 64;     // 640 B of ws used
    if (zb > ws_size) zb = ws_size;
    hipMemsetAsync(d_ws, 0, zb, stream);

    // Scratch lives in the quantized region of `out` (dead until vq_scatter,
    // which runs LAST, overwrites it). 16B-align the base so uint4/float4
    // staging loads are aligned. Layout: WhiG | WloG | Bsc | gHistP | flagList.
    uintptr_t sbase = ((uintptr_t)(out + OFF_Q) + 15) & ~(uintptr_t)15;
    unsigned short* WhiG = (unsigned short*)sbase;                // 64 KiB
    unsigned short* WloG = WhiG + (size_t)KCODES * DIM;           // 64 KiB
    float* Bsc = (float*)(WloG + (size_t)KCODES * DIM);           // 2 KiB
    unsigned* gHistP = (unsigned*)(Bsc + KCODES);                 // 128 KiB
    int* flagList = (int*)(gHistP + (size_t)NPART * KCODES);      // <=1 MiB
    hipMemsetAsync(gHistP, 0, (size_t)NPART * KCODES * sizeof(unsigned), stream);

    vq_prep<<<2, 256, 0, stream>>>(W, WhiG, WloG, Bsc);
    vq_argmin<<<NBLOCKS, THREADS, 0, stream>>>(X, WhiG, WloG, Bsc, out,
                                               sseAcc, gHistP, flagList, gCnt);
    vq_fixup<<<NBLOCKS, 512, 0, stream>>>(X, W, Bsc, out, sseP, gHistP,
                                          flagList, gCnt);
    vq_finalize<<<1, 512, 0, stream>>>(sseAcc, sseP, gHistP, out);
    vq_scatter<<<(N_ROWS * DIM) / 256, 256, 0, stream>>>(W, out);
}

// Round 7
// 269.161 us; speedup vs baseline: 1.7346x; 1.7346x over previous
//
#include <hip/hip_runtime.h>

#define N_ROWS 262144
#define DIM 64
#define KCODES 512
#define THREADS 512
#define BLK_ROWS 128                       // 8 waves x 16 rows
#define NBLOCKS (N_ROWS / BLK_ROWS)        // 2048
#define CHUNK 128                          // codes staged in LDS per pass
#define NCHUNK (KCODES / CHUNK)            // 4
#define NPART 64                           // partial histograms / sse slots (contention spread)
// error budget: np-e rounding (<=ulp(128)*2 ~3.0e-5) + biased-key quant (3.05e-5)
// + 3-pass bf16 (~2e-6) + flag-gap quantum (3.05e-5) ~= 9.4e-5 < MARGIN_T
#define MARGIN_T 1.25e-4f

// d_out is FLOAT32. Flat layout in return order:
// [0] loss | [1 .. 1+N*D) quantized | [1+N*D] norm_perplexity | [2+N*D ..) indices
#define OFF_Q 1
#define OFF_PERP (1 + (size_t)N_ROWS * DIM)
#define OFF_IDX (2 + (size_t)N_ROWS * DIM)

typedef __attribute__((ext_vector_type(8))) short bf16x8;
typedef __attribute__((ext_vector_type(4))) float f32x4;

// ---------- numerics helpers (numpy-exact machinery, carried over) ----------

// numpy pairwise sum of squares for n=64 (loops.c.src): 8 strided accumulators,
// sequential adds, fixed combine tree. contract(off): square rounds BEFORE add.
__device__ __forceinline__ float np_sum_sq64(const float* __restrict__ v) {
#pragma clang fp contract(off)
    float r[8];
#pragma unroll
    for (int l = 0; l < 8; ++l) r[l] = v[l] * v[l];
#pragma unroll
    for (int k = 1; k < 8; ++k) {
#pragma unroll
        for (int l = 0; l < 8; ++l) {
            float sq = v[8 * k + l] * v[8 * k + l];
            r[l] = r[l] + sq;
        }
    }
    return ((r[0] + r[1]) + (r[2] + r[3])) + ((r[4] + r[5]) + (r[6] + r[7]));
}

// fp32 -> bf16 bits, round-to-nearest-even
__device__ __forceinline__ unsigned short f2bf(float f) {
    unsigned u = __float_as_uint(f);
    u += 0x7FFFu + ((u >> 16) & 1u);
    return (unsigned short)(u >> 16);
}
__device__ __forceinline__ float bf2f(unsigned short h) {
    return __uint_as_float((unsigned)h << 16);
}

// biased sortable key: t in (-0.5, 0.5) guaranteed (|t| <= B + 2|x.w| <= 0.38
// hard bound), so t+0.5 is a positive float -> IEEE bits are order-isomorphic.
// Low 9 mantissa bits replaced by code idx (first-index tie-break for free).
// Quantization <= 511*ulp(0.86) ~= 3.05e-5, covered by MARGIN_T.
__device__ __forceinline__ unsigned t2key(float t, unsigned idx) {
    return (__float_as_uint(t + 0.5f) & 0xFFFFFE00u) | idx;   // v_add + v_and_or
}
__device__ __forceinline__ float key2t(unsigned key) {
    // (t+0.5) in [0.25,1) -> subtracting 0.5 is exact (Sterbenz)
    return __uint_as_float(key & 0xFFFFFE00u) - 0.5f;
}

// ---------- prep: W_hi/W_lo (bf16 of -2W, split) + numpy ||w||^2 ----------

__global__ __launch_bounds__(256) void vq_prep(const float* __restrict__ W,
        unsigned short* __restrict__ WhiG, unsigned short* __restrict__ WloG,
        float* __restrict__ Bsc) {
    int c = blockIdx.x * 256 + threadIdx.x;
    if (c >= KCODES) return;
    const float* w = W + (size_t)c * DIM;
    Bsc[c] = np_sum_sq64(w);                 // numpy summation order
#pragma unroll 4
    for (int d = 0; d < DIM; ++d) {
        float v = -2.0f * w[d];              // exact scale
        unsigned short hi = f2bf(v);
        unsigned short lo = f2bf(v - bf2f(hi));   // split residual, exact subtract
        WhiG[c * DIM + d] = hi;
        WloG[c * DIM + d] = lo;
    }
}

// ---------- main: MFMA distance + packed-key min1/min2 argmin + SSE + hist ----------
// Wave w owns rows [16w,16w+16). MFMA 16x16x32_bf16: A = -2W (M=codes),
// B = X (N=rows), C-init = B_j. 3 passes: ah*xh + ah*xl + al*xh.
// D layout (m89-verified): col=lane&15 (row n), row=(lane>>4)*4+reg (code m).
// SSE_row = ||x||^2 + t1 (unflagged rows); flagged rows go to the global list.

__global__ __launch_bounds__(THREADS, 4) void vq_argmin(
    const float* __restrict__ X,
    const unsigned short* __restrict__ WhiG,
    const unsigned short* __restrict__ WloG,
    const float* __restrict__ Bsc,
    float* __restrict__ out,
    double* __restrict__ sseAcc,
    unsigned* __restrict__ gHistP,
    int* __restrict__ flagList,
    unsigned* __restrict__ gCnt) {

    __shared__ __align__(16) unsigned short sHi[CHUNK * DIM];  // 16 KiB, swizzled
    __shared__ __align__(16) unsigned short sLo[CHUNK * DIM];  // 16 KiB, swizzled
    __shared__ __align__(16) float sX[BLK_ROWS * DIM];         // 32 KiB, swizzled
    __shared__ __align__(16) float sB[KCODES];                 // 2 KiB
    __shared__ unsigned sHist[KCODES];                         // 2 KiB
    __shared__ int sFlagRows[BLK_ROWS];
    __shared__ unsigned sCnt, sBase;
    __shared__ double sSseW[8];

    const int tid = threadIdx.x;
    const int w = tid >> 6;          // wave 0..7
    const int l = tid & 63;          // lane
    const int q = l >> 4;            // lane quad 0..3
    const int r16 = l & 15;          // n / m sub-index
    const int R0 = blockIdx.x * BLK_ROWS;

    // ---- stage X tile (coalesced load, XOR-swizzled store: byte ^= (r&7)<<5) ----
    {
        const float4* g = (const float4*)(X + (size_t)R0 * DIM);
        char* base = (char*)sX;
#pragma unroll
        for (int i = 0; i < (BLK_ROWS * DIM / 4) / THREADS; ++i) {   // 4
            int fidx = tid + THREADS * i;                            // [0,2048)
            int r = fidx >> 4, c4 = fidx & 15;
            int off = (r * 256 + c4 * 16) ^ ((r & 7) << 5);
            *(float4*)(base + off) = g[fidx];
        }
        sB[tid] = Bsc[tid];   // THREADS == KCODES
        sHist[tid] = 0u;
        if (tid == 0) sCnt = 0u;
    }
    __syncthreads();

    // ---- per-lane X fragments: row r = 16w + (l&15), k = 32h + 8q + j ----
    // asum = lane's partial ||x||^2 over its 16 covered dims.
    bf16x8 xh[2], xl[2];
    float asum = 0.f;
    {
        const int r = w * 16 + r16;
        const char* base = (const char*)sX;
#pragma unroll
        for (int h = 0; h < 2; ++h) {
            int b0 = (r * 256 + h * 128 + q * 32) ^ ((r & 7) << 5);
            float4 fa = *(const float4*)(base + b0);
            float4 fb = *(const float4*)(base + b0 + 16);   // bit4 untouched by swizzle
            float f[8] = {fa.x, fa.y, fa.z, fa.w, fb.x, fb.y, fb.z, fb.w};
            bf16x8 hi8, lo8;
#pragma unroll
            for (int j = 0; j < 8; ++j) {
                asum = fmaf(f[j], f[j], asum);
                unsigned short hi = f2bf(f[j]);
                unsigned short lo = f2bf(f[j] - bf2f(hi));
                hi8[j] = (short)hi; lo8[j] = (short)lo;
            }
            xh[h] = hi8; xl[h] = lo8;
        }
    }

    unsigned min1 = 0xFFFFFFFFu, min2 = 0xFFFFFFFFu;

    for (int cc = 0; cc < NCHUNK; ++cc) {
        const int c0 = cc * CHUNK;
        __syncthreads();
        {   // stage -2W chunk hi+lo (coalesced uint4, swizzle: byte ^= (c&7)<<4)
            const uint4* gh = (const uint4*)(WhiG + (size_t)c0 * DIM);
            const uint4* gl = (const uint4*)(WloG + (size_t)c0 * DIM);
            char* bh = (char*)sHi; char* bl = (char*)sLo;
#pragma unroll
            for (int i = 0; i < (CHUNK * DIM / 8) / THREADS; ++i) {  // 2
                int idx = tid + THREADS * i;                          // uint4 idx
                int c = idx >> 3, k8 = idx & 7;
                int off = (c * 128 + k8 * 16) ^ ((c & 7) << 4);
                *(uint4*)(bh + off) = gh[idx];
                *(uint4*)(bl + off) = gl[idx];
            }
        }
        __syncthreads();

#pragma unroll
        for (int ct = 0; ct < CHUNK / 16; ++ct) {
            const int cloc = ct * 16 + r16;     // chunk-local code row of A frag
            const char* bh = (const char*)sHi;
            const char* bl = (const char*)sLo;
            const int sw = (cloc & 7) << 4;
            int o0 = (cloc * 128 + 16 * q) ^ sw;          // k-half 0
            int o1 = (cloc * 128 + 64 + 16 * q) ^ sw;     // k-half 1
            bf16x8 ah0 = *(const bf16x8*)(bh + o0);
            bf16x8 ah1 = *(const bf16x8*)(bh + o1);
            bf16x8 al0 = *(const bf16x8*)(bl + o0);
            bf16x8 al1 = *(const bf16x8*)(bl + o1);

            // C-init = B_j for this lane's 4 codes -> acc ends as t = B - 2*dot
            f32x4 acc = *(const f32x4*)&sB[c0 + ct * 16 + q * 4];

            acc = __builtin_amdgcn_mfma_f32_16x16x32_bf16(ah0, xh[0], acc, 0, 0, 0);
            acc = __builtin_amdgcn_mfma_f32_16x16x32_bf16(ah1, xh[1], acc, 0, 0, 0);
            acc = __builtin_amdgcn_mfma_f32_16x16x32_bf16(ah0, xl[0], acc, 0, 0, 0);
            acc = __builtin_amdgcn_mfma_f32_16x16x32_bf16(ah1, xl[1], acc, 0, 0, 0);
            acc = __builtin_amdgcn_mfma_f32_16x16x32_bf16(al0, xh[0], acc, 0, 0, 0);
            acc = __builtin_amdgcn_mfma_f32_16x16x32_bf16(al1, xh[1], acc, 0, 0, 0);

            // biased-key pack (2 VALU each) + min/max tournament: top-2 of
            // {min1,min2,k0..k3} in 12 ops (vs 4x sequential insert = 28).
            const unsigned jbase = (unsigned)(c0 + ct * 16 + q * 4);
            unsigned k0 = t2key(acc[0], jbase + 0u);
            unsigned k1 = t2key(acc[1], jbase + 1u);
            unsigned k2 = t2key(acc[2], jbase + 2u);
            unsigned k3 = t2key(acc[3], jbase + 3u);
            unsigned lo01 = k0 < k1 ? k0 : k1, hi01 = k0 < k1 ? k1 : k0;
            unsigned lo23 = k2 < k3 ? k2 : k3, hi23 = k2 < k3 ? k3 : k2;
            unsigned m1 = lo01 < lo23 ? lo01 : lo23;     // min of 4
            unsigned mm = lo01 < lo23 ? lo23 : lo01;     // max of the two lows
            unsigned hh = hi01 < hi23 ? hi01 : hi23;     // min of the two highs
            unsigned m2 = hh < mm ? hh : mm;             // 2nd-min of 4
            unsigned nm = min1 < m1 ? m1 : min1;         // max(firsts)
            min1 = min1 < m1 ? min1 : m1;
            unsigned sm = min2 < m2 ? min2 : m2;         // min(seconds)
            min2 = sm < nm ? sm : nm;
        }
    }

    // ---- merge the 4 lane-subsets of each row (lanes l, l^16, l^32, l^48) ----
    // Also merges the 4 partial ||x||^2 sums into the full per-row A.
#pragma unroll
    for (int d = 16; d <= 32; d <<= 1) {
        unsigned o1 = (unsigned)__shfl_xor((int)min1, d, 64);
        unsigned o2 = (unsigned)__shfl_xor((int)min2, d, 64);
        asum += __shfl_xor(asum, d, 64);
        unsigned n1 = min1 < o1 ? min1 : o1;
        unsigned mx = min1 > o1 ? min1 : o1;
        unsigned mn = min2 < o2 ? min2 : o2;
        unsigned n2 = mx < mn ? mx : mn;
        min1 = n1; min2 = n2;
    }

    const unsigned best = min1 & 511u;
    const float t1 = key2t(min1), t2 = key2t(min2);
    const bool flagged = (t2 < t1 + MARGIN_T);

    float ssev = 0.f;
    if (q == 0) {   // row owner: lanes 0..15 -> 16 consecutive rows, coalesced
        const int row = R0 + w * 16 + r16;
        out[OFF_IDX + row] = (float)best;    // flagged rows corrected by fixup
        if (!flagged) {
            ssev = asum + t1;                 // SSE = ||x||^2 + (B - 2*dot)
            atomicAdd(&sHist[best], 1u);
        } else {
            unsigned s = atomicAdd(&sCnt, 1u);
            sFlagRows[s] = row;
        }
    }
    // per-wave SSE reduce (owners hold nonzero), then block-level flush
#pragma unroll
    for (int off = 32; off; off >>= 1) ssev += __shfl_down(ssev, off);
    if (l == 0) sSseW[w] = (double)ssev;
    __syncthreads();

    if (tid == 0) sBase = atomicAdd(gCnt, sCnt);   // global list segment
    {   // flush histogram to partial hist (spreads atomic contention 64x)
        unsigned c = sHist[tid];
        if (c) atomicAdd(&gHistP[(blockIdx.x & (NPART - 1)) * KCODES + tid], c);
    }
    __syncthreads();
    if (tid < (int)sCnt) flagList[sBase + tid] = sFlagRows[tid];
    if (tid == 0) {
        double s = 0.0;
#pragma unroll
        for (int i = 0; i < 8; ++i) s += sSseW[i];
        atomicAdd(sseAcc, s);                 // one fp64 atomic per block (2048 total)
    }
}

// ---------- fixup: exact numpy-fp32 argmin over ALL 512 codes, listed rows ----------
// Grid-stride over the globally-compacted flag list, one 512-thread block per
// row, ONE CODE PER THREAD. The X row lives in REGISTERS: every xr index is
// COMPILE-TIME (full unroll) so SROA scalarizes the array. Round-6 bug: a
// partial `#pragma unroll 4` left the loop index runtime -> rule #20 -> xr
// demoted to scratch (VGPR=44, 1.18 GB scratch traffic, 270us). Full unroll +
// __launch_bounds__(512,2) (256-VGPR budget, ~150 used) keeps it in VGPRs
// without round-3's forced spill. X loads are wave-broadcast (same 256B line).
// Per-code fp64 fma order is bit-identical to numpy. u64-key reduce: wave
// shfl + LDS cross-wave, first-index tie-break. Contributes SSE (exact e) +
// histogram.

__global__ __launch_bounds__(512, 2) void vq_fixup(
    const float* __restrict__ X, const float* __restrict__ W,
    const float* __restrict__ Bsc, float* __restrict__ out,
    double* __restrict__ sseP, unsigned* __restrict__ gHistP,
    const int* __restrict__ flagList, const unsigned* __restrict__ gCnt) {
    __shared__ unsigned long long sKeyW[8];
    const unsigned total = *gCnt;
    const int t = threadIdx.x;               // == code id
    const int wv = t >> 6, l = t & 63;

    for (unsigned i = blockIdx.x; i < total; i += gridDim.x) {
        const int row = flagList[i];

        float xr[DIM];                       // SROA -> 64 VGPRs (static idx only)
        {
            const float4* Xr4 = (const float4*)(X + (size_t)row * DIM);
#pragma unroll
            for (int k4 = 0; k4 < 16; ++k4) {
                float4 v = Xr4[k4];
                xr[4 * k4 + 0] = v.x; xr[4 * k4 + 1] = v.y;
                xr[4 * k4 + 2] = v.z; xr[4 * k4 + 3] = v.w;
            }
        }
        const float A = np_sum_sq64(xr);     // numpy order, identical bits all threads

        // exact np_e for code t: fp64 dot in numpy's sequential order.
        // FULL unroll: all xr indices compile-time (rule #20).
        double acc = 0.0;
        {
            const float4* wr = (const float4*)(W + (size_t)t * DIM);
#pragma unroll
            for (int k4 = 0; k4 < 16; ++k4) {
                float4 f = wr[k4];
                acc = fma((double)f.x, (double)xr[4 * k4 + 0], acc);
                acc = fma((double)f.y, (double)xr[4 * k4 + 1], acc);
                acc = fma((double)f.z, (double)xr[4 * k4 + 2], acc);
                acc = fma((double)f.w, (double)xr[4 * k4 + 3], acc);
            }
        }
        unsigned long long bk;
        {
#pragma clang fp contract(off)
            float C2 = (float)(2.0 * acc);
            float e = (A + Bsc[t]) - C2;     // np fp32: (A+B) then subtract
            int iu = __float_as_int(e);
            unsigned u = ((unsigned)iu) ^ (((unsigned)(iu >> 31)) | 0x80000000u);
            bk = ((unsigned long long)u << 32) | (unsigned)t;
        }
#pragma unroll
        for (int d = 1; d < 64; d <<= 1) {
            unsigned long long o =
                (unsigned long long)__shfl_xor((long long)bk, d, 64);
            bk = bk < o ? bk : o;
        }
        if (l == 0) sKeyW[wv] = bk;
        __syncthreads();
        if (t == 0) {
            unsigned long long b = sKeyW[0];
#pragma unroll
            for (int k = 1; k < 8; ++k) if (sKeyW[k] < b) b = sKeyW[k];
            unsigned bestc = (unsigned)(b & 511ULL);
            unsigned u = (unsigned)(b >> 32);
            unsigned fb = (u & 0x80000000u) ? (u & 0x7FFFFFFFu) : ~u;
            float ebest = __uint_as_float(fb);   // exact np-fp32 e of the winner
            out[OFF_IDX + row] = (float)bestc;
            atomicAdd(&gHistP[(i & (NPART - 1)) * KCODES + bestc], 1u);
            atomicAdd(&sseP[i & (NPART - 1)], (double)ebest);   // SSE = e
        }
        __syncthreads();                     // protect sKeyW before next iter
    }
}

// ---------- scatter: pure gather W[best] -> Q (no atomics, no X read) ----------
// One wave per row. Index load is wave-uniform, W gather is one coalesced
// 256B read (L2-hot), store coalesced. Runs on FINAL indices (post-fixup).

__global__ __launch_bounds__(256) void vq_scatter(
    const float* __restrict__ W, float* __restrict__ out) {
    const int gid = blockIdx.x * 256 + threadIdx.x;
    const int row = gid >> 6;
    const int lane = gid & 63;
    int idx = (int)out[OFF_IDX + row];
    if ((unsigned)idx >= KCODES) idx = KCODES - 1;   // safety clamp
    out[OFF_Q + (size_t)row * DIM + lane] = W[(size_t)idx * DIM + lane];
}

// ---------- finalize: sum partial hists -> perplexity; sse -> loss ----------

__global__ __launch_bounds__(512) void vq_finalize(
    const double* __restrict__ sseAcc, const double* __restrict__ sseP,
    const unsigned* __restrict__ gHistP, float* __restrict__ out) {
    __shared__ float partial[8];
    const int t = threadIdx.x;
    unsigned c = 0;
#pragma unroll 8
    for (int p = 0; p < NPART; ++p) c += gHistP[p * KCODES + t];
    float pf = (float)c * (1.0f / (float)N_ROWS);
    float v = pf * logf(pf + 1e-10f);
#pragma unroll
    for (int off = 32; off; off >>= 1) v += __shfl_down(v, off);
    if ((t & 63) == 0) partial[t >> 6] = v;
    __syncthreads();
    if (t == 0) {
        float s = 0.f;
#pragma unroll
        for (int i = 0; i < 8; ++i) s += partial[i];
        out[OFF_PERP] = expf(-s) * (1.0f / (float)KCODES);
        double s2 = sseAcc[0];
#pragma unroll
        for (int i = 0; i < NPART; ++i) s2 += sseP[i];
        out[0] = (float)(1.25 * s2 * (1.0 / ((double)N_ROWS * (double)DIM)));
    }
}

extern "C" void kernel_launch(void* const* d_in, const int* in_sizes, int n_in,
                              void* d_out, int out_size, void* d_ws, size_t ws_size,
                              hipStream_t stream) {
    const float* X = (const float*)d_in[0];
    const float* W = (const float*)d_in[1];
    float* out = (float*)d_out;
    double* sseAcc = (double*)d_ws;
    double* sseP = (double*)((char*)d_ws + 64);       // 64 slots
    unsigned* gCnt = (unsigned*)((char*)d_ws + 64 + NPART * sizeof(double));

    size_t zb = 64 + NPART * sizeof(double) + 64;     // 640 B of ws used
    if (zb > ws_size) zb = ws_size;
    hipMemsetAsync(d_ws, 0, zb, stream);

    // Scratch lives in the quantized region of `out` (dead until vq_scatter,
    // which runs LAST, overwrites it). 16B-align the base so uint4/float4
    // staging loads are aligned. Layout: WhiG | WloG | Bsc | gHistP | flagList.
    uintptr_t sbase = ((uintptr_t)(out + OFF_Q) + 15) & ~(uintptr_t)15;
    unsigned short* WhiG = (unsigned short*)sbase;                // 64 KiB
    unsigned short* WloG = WhiG + (size_t)KCODES * DIM;           // 64 KiB
    float* Bsc = (float*)(WloG + (size_t)KCODES * DIM);           // 2 KiB
    unsigned* gHistP = (unsigned*)(Bsc + KCODES);                 // 128 KiB
    int* flagList = (int*)(gHistP + (size_t)NPART * KCODES);      // <=1 MiB
    hipMemsetAsync(gHistP, 0, (size_t)NPART * KCODES * sizeof(unsigned), stream);

    vq_prep<<<2, 256, 0, stream>>>(W, WhiG, WloG, Bsc);
    vq_argmin<<<NBLOCKS, THREADS, 0, stream>>>(X, WhiG, WloG, Bsc, out,
                                               sseAcc, gHistP, flagList, gCnt);
    vq_fixup<<<NBLOCKS, 512, 0, stream>>>(X, W, Bsc, out, sseP, gHistP,
                                          flagList, gCnt);
    vq_finalize<<<1, 512, 0, stream>>>(sseAcc, sseP, gHistP, out);
    vq_scatter<<<(N_ROWS * DIM) / 256, 256, 0, stream>>>(W, out);
}

// Round 8
// 241.831 us; speedup vs baseline: 1.9306x; 1.1130x over previous
//
#include <hip/hip_runtime.h>

#define N_ROWS 262144
#define DIM 64
#define KCODES 512
#define THREADS 512
#define BLK_ROWS 256                       // 8 waves x 32 rows (2 B-frags/wave)
#define NBLOCKS (N_ROWS / BLK_ROWS)        // 1024
#define CHUNK 128                          // codes staged in LDS per pass
#define NCHUNK (KCODES / CHUNK)            // 4
#define NPART 64                           // partial histograms / sse slots (contention spread)
// error budget: np-e rounding (<=ulp(128)*2 ~3.0e-5) + biased-key quant (3.05e-5)
// + 3-pass bf16 (~2e-6) + flag-gap quantum (3.05e-5) ~= 9.4e-5 < MARGIN_T
#define MARGIN_T 1.25e-4f

// d_out is FLOAT32. Flat layout in return order:
// [0] loss | [1 .. 1+N*D) quantized | [1+N*D] norm_perplexity | [2+N*D ..) indices
#define OFF_Q 1
#define OFF_PERP (1 + (size_t)N_ROWS * DIM)
#define OFF_IDX (2 + (size_t)N_ROWS * DIM)

typedef __attribute__((ext_vector_type(8))) short bf16x8;
typedef __attribute__((ext_vector_type(4))) float f32x4;

// ---------- numerics helpers (numpy-exact machinery, carried over) ----------

// numpy pairwise sum of squares for n=64 (loops.c.src): 8 strided accumulators,
// sequential adds, fixed combine tree. contract(off): square rounds BEFORE add.
__device__ __forceinline__ float np_sum_sq64(const float* __restrict__ v) {
#pragma clang fp contract(off)
    float r[8];
#pragma unroll
    for (int l = 0; l < 8; ++l) r[l] = v[l] * v[l];
#pragma unroll
    for (int k = 1; k < 8; ++k) {
#pragma unroll
        for (int l = 0; l < 8; ++l) {
            float sq = v[8 * k + l] * v[8 * k + l];
            r[l] = r[l] + sq;
        }
    }
    return ((r[0] + r[1]) + (r[2] + r[3])) + ((r[4] + r[5]) + (r[6] + r[7]));
}

// fp32 -> bf16 bits, round-to-nearest-even
__device__ __forceinline__ unsigned short f2bf(float f) {
    unsigned u = __float_as_uint(f);
    u += 0x7FFFu + ((u >> 16) & 1u);
    return (unsigned short)(u >> 16);
}
__device__ __forceinline__ float bf2f(unsigned short h) {
    return __uint_as_float((unsigned)h << 16);
}

// biased sortable key: t in (-0.5, 0.5) guaranteed (|t| <= B + 2|x.w| <= 0.38
// hard bound), so t+0.5 is a positive float -> IEEE bits are order-isomorphic.
// The +0.5 bias is FOLDED INTO THE MFMA C-INIT (sB holds B+0.5), so packing is
// a single v_and_or per value. Low 9 mantissa bits replaced by code idx
// (first-index tie-break for free). Quantization <= 511*ulp(0.86) ~= 3.05e-5,
// covered by MARGIN_T.
__device__ __forceinline__ unsigned t2key_biased(float tb, unsigned idx) {
    return (__float_as_uint(tb) & 0xFFFFFE00u) | idx;   // tb = t + 0.5 already
}
__device__ __forceinline__ float key2t(unsigned key) {
    // (t+0.5) in (0.12,0.88) -> subtracting 0.5 rounds once (<=1.5e-8), negligible
    return __uint_as_float(key & 0xFFFFFE00u) - 0.5f;
}

// ---------- prep: W_hi/W_lo (bf16 of -2W, split) + numpy ||w||^2 ----------

__global__ __launch_bounds__(256) void vq_prep(const float* __restrict__ W,
        unsigned short* __restrict__ WhiG, unsigned short* __restrict__ WloG,
        float* __restrict__ Bsc) {
    int c = blockIdx.x * 256 + threadIdx.x;
    if (c >= KCODES) return;
    const float* w = W + (size_t)c * DIM;
    Bsc[c] = np_sum_sq64(w);                 // numpy summation order
#pragma unroll 4
    for (int d = 0; d < DIM; ++d) {
        float v = -2.0f * w[d];              // exact scale
        unsigned short hi = f2bf(v);
        unsigned short lo = f2bf(v - bf2f(hi));   // split residual, exact subtract
        WhiG[c * DIM + d] = hi;
        WloG[c * DIM + d] = lo;
    }
}

// ---------- main: MFMA distance + packed-key min1/min2 argmin + SSE + hist ----------
// Wave w owns rows [32w, 32w+32): TWO 16-row B-fragments sharing each A-frag
// read (halves LDS read traffic vs r7: LDS BW was the binding pipe — MfmaUtil
// 27.6% == exact MFMA-floor/dur ratio, 2.1 GB ds_read at ~69 TB/s ~ the rest).
// MFMA 16x16x32_bf16: A = -2W (M=codes), B = X (N=rows), C-init = B_j + 0.5.
// 3 passes: ah*xh + ah*xl + al*xh. D layout (m89-verified): col=lane&15 (row n),
// row=(lane>>4)*4+reg (code m). X fragments load DIRECT from global (sX staging
// dropped: 70.6->37 KB LDS). SSE_row = ||x||^2 + t1 (unflagged rows); flagged
// rows go to the global list.

__global__ __launch_bounds__(THREADS, 4) void vq_argmin(
    const float* __restrict__ X,
    const unsigned short* __restrict__ WhiG,
    const unsigned short* __restrict__ WloG,
    const float* __restrict__ Bsc,
    float* __restrict__ out,
    double* __restrict__ sseAcc,
    unsigned* __restrict__ gHistP,
    int* __restrict__ flagList,
    unsigned* __restrict__ gCnt) {

    __shared__ __align__(16) unsigned short sHi[CHUNK * DIM];  // 16 KiB, swizzled
    __shared__ __align__(16) unsigned short sLo[CHUNK * DIM];  // 16 KiB, swizzled
    __shared__ __align__(16) float sB[KCODES];                 // 2 KiB (B + 0.5)
    __shared__ unsigned sHist[KCODES];                         // 2 KiB
    __shared__ int sFlagRows[BLK_ROWS];                        // 1 KiB
    __shared__ unsigned sCnt, sBase;
    __shared__ double sSseW[8];

    const int tid = threadIdx.x;
    const int w = tid >> 6;          // wave 0..7
    const int l = tid & 63;          // lane
    const int q = l >> 4;            // lane quad 0..3
    const int r16 = l & 15;          // n / m sub-index
    const int R0 = blockIdx.x * BLK_ROWS;

    sB[tid] = Bsc[tid] + 0.5f;       // THREADS == KCODES; bias folded into C-init
    sHist[tid] = 0u;
    if (tid == 0) sCnt = 0u;

    // ---- per-lane X fragments DIRECT from global: row rA = 32w + r16 (+16 for
    // group B), dims k = 32h + 8q + j. Each (row,dim) read by exactly one lane.
    // asum* = lane's partial ||x||^2 over its 16 covered dims of that row.
    bf16x8 xhA[2], xlA[2], xhB[2], xlB[2];
    float asumA = 0.f, asumB = 0.f;
    {
        const float* xrA = X + (size_t)(R0 + w * 32 + r16) * DIM;
        const float* xrB = xrA + 16 * DIM;
#pragma unroll
        for (int h = 0; h < 2; ++h) {
            float4 fa = *(const float4*)(xrA + 32 * h + 8 * q);
            float4 fb = *(const float4*)(xrA + 32 * h + 8 * q + 4);
            float fA[8] = {fa.x, fa.y, fa.z, fa.w, fb.x, fb.y, fb.z, fb.w};
            float4 ga = *(const float4*)(xrB + 32 * h + 8 * q);
            float4 gb = *(const float4*)(xrB + 32 * h + 8 * q + 4);
            float fB[8] = {ga.x, ga.y, ga.z, ga.w, gb.x, gb.y, gb.z, gb.w};
            bf16x8 hiA, loA, hiB, loB;
#pragma unroll
            for (int j = 0; j < 8; ++j) {
                asumA = fmaf(fA[j], fA[j], asumA);
                unsigned short h1 = f2bf(fA[j]);
                hiA[j] = (short)h1; loA[j] = (short)f2bf(fA[j] - bf2f(h1));
                asumB = fmaf(fB[j], fB[j], asumB);
                unsigned short h2 = f2bf(fB[j]);
                hiB[j] = (short)h2; loB[j] = (short)f2bf(fB[j] - bf2f(h2));
            }
            xhA[h] = hiA; xlA[h] = loA;
            xhB[h] = hiB; xlB[h] = loB;
        }
    }

    unsigned min1A = 0xFFFFFFFFu, min2A = 0xFFFFFFFFu;
    unsigned min1B = 0xFFFFFFFFu, min2B = 0xFFFFFFFFu;

    for (int cc = 0; cc < NCHUNK; ++cc) {
        const int c0 = cc * CHUNK;
        __syncthreads();
        {   // stage -2W chunk hi+lo (coalesced uint4, swizzle: byte ^= (c&7)<<4)
            const uint4* gh = (const uint4*)(WhiG + (size_t)c0 * DIM);
            const uint4* gl = (const uint4*)(WloG + (size_t)c0 * DIM);
            char* bh = (char*)sHi; char* bl = (char*)sLo;
#pragma unroll
            for (int i = 0; i < (CHUNK * DIM / 8) / THREADS; ++i) {  // 2
                int idx = tid + THREADS * i;                          // uint4 idx
                int c = idx >> 3, k8 = idx & 7;
                int off = (c * 128 + k8 * 16) ^ ((c & 7) << 4);
                *(uint4*)(bh + off) = gh[idx];
                *(uint4*)(bl + off) = gl[idx];
            }
        }
        __syncthreads();

#pragma unroll
        for (int ct = 0; ct < CHUNK / 16; ++ct) {
            const int cloc = ct * 16 + r16;     // chunk-local code row of A frag
            const char* bh = (const char*)sHi;
            const char* bl = (const char*)sLo;
            const int sw = (cloc & 7) << 4;
            int o0 = (cloc * 128 + 16 * q) ^ sw;          // k-half 0
            int o1 = (cloc * 128 + 64 + 16 * q) ^ sw;     // k-half 1
            bf16x8 ah0 = *(const bf16x8*)(bh + o0);
            bf16x8 ah1 = *(const bf16x8*)(bh + o1);
            bf16x8 al0 = *(const bf16x8*)(bl + o0);
            bf16x8 al1 = *(const bf16x8*)(bl + o1);

            // C-init = B_j + 0.5 -> acc ends as biased t = (B - 2*dot) + 0.5
            f32x4 accA = *(const f32x4*)&sB[c0 + ct * 16 + q * 4];
            f32x4 accB = accA;

            accA = __builtin_amdgcn_mfma_f32_16x16x32_bf16(ah0, xhA[0], accA, 0, 0, 0);
            accB = __builtin_amdgcn_mfma_f32_16x16x32_bf16(ah0, xhB[0], accB, 0, 0, 0);
            accA = __builtin_amdgcn_mfma_f32_16x16x32_bf16(ah1, xhA[1], accA, 0, 0, 0);
            accB = __builtin_amdgcn_mfma_f32_16x16x32_bf16(ah1, xhB[1], accB, 0, 0, 0);
            accA = __builtin_amdgcn_mfma_f32_16x16x32_bf16(ah0, xlA[0], accA, 0, 0, 0);
            accB = __builtin_amdgcn_mfma_f32_16x16x32_bf16(ah0, xlB[0], accB, 0, 0, 0);
            accA = __builtin_amdgcn_mfma_f32_16x16x32_bf16(ah1, xlA[1], accA, 0, 0, 0);
            accB = __builtin_amdgcn_mfma_f32_16x16x32_bf16(ah1, xlB[1], accB, 0, 0, 0);
            accA = __builtin_amdgcn_mfma_f32_16x16x32_bf16(al0, xhA[0], accA, 0, 0, 0);
            accB = __builtin_amdgcn_mfma_f32_16x16x32_bf16(al0, xhB[0], accB, 0, 0, 0);
            accA = __builtin_amdgcn_mfma_f32_16x16x32_bf16(al1, xhA[1], accA, 0, 0, 0);
            accB = __builtin_amdgcn_mfma_f32_16x16x32_bf16(al1, xhB[1], accB, 0, 0, 0);

            // key pack (1 v_and_or each, bias already in acc) + min/max
            // tournament: top-2 of {min,k0..k3} in 10 ops per row-group.
            const unsigned jbase = (unsigned)(c0 + ct * 16 + q * 4);
            {
                unsigned k0 = t2key_biased(accA[0], jbase + 0u);
                unsigned k1 = t2key_biased(accA[1], jbase + 1u);
                unsigned k2 = t2key_biased(accA[2], jbase + 2u);
                unsigned k3 = t2key_biased(accA[3], jbase + 3u);
                unsigned lo01 = k0 < k1 ? k0 : k1, hi01 = k0 < k1 ? k1 : k0;
                unsigned lo23 = k2 < k3 ? k2 : k3, hi23 = k2 < k3 ? k3 : k2;
                unsigned m1 = lo01 < lo23 ? lo01 : lo23;
                unsigned mm = lo01 < lo23 ? lo23 : lo01;
                unsigned hh = hi01 < hi23 ? hi01 : hi23;
                unsigned m2 = hh < mm ? hh : mm;
                unsigned nm = min1A < m1 ? m1 : min1A;
                min1A = min1A < m1 ? min1A : m1;
                unsigned sm = min2A < m2 ? min2A : m2;
                min2A = sm < nm ? sm : nm;
            }
            {
                unsigned k0 = t2key_biased(accB[0], jbase + 0u);
                unsigned k1 = t2key_biased(accB[1], jbase + 1u);
                unsigned k2 = t2key_biased(accB[2], jbase + 2u);
                unsigned k3 = t2key_biased(accB[3], jbase + 3u);
                unsigned lo01 = k0 < k1 ? k0 : k1, hi01 = k0 < k1 ? k1 : k0;
                unsigned lo23 = k2 < k3 ? k2 : k3, hi23 = k2 < k3 ? k3 : k2;
                unsigned m1 = lo01 < lo23 ? lo01 : lo23;
                unsigned mm = lo01 < lo23 ? lo23 : lo01;
                unsigned hh = hi01 < hi23 ? hi01 : hi23;
                unsigned m2 = hh < mm ? hh : mm;
                unsigned nm = min1B < m1 ? m1 : min1B;
                min1B = min1B < m1 ? min1B : m1;
                unsigned sm = min2B < m2 ? min2B : m2;
                min2B = sm < nm ? sm : nm;
            }
        }
    }

    // ---- merge the 4 lane-subsets of each row (lanes l, l^16, l^32, l^48) ----
    // Also merges the 4 partial ||x||^2 sums into the full per-row A.
#pragma unroll
    for (int d = 16; d <= 32; d <<= 1) {
        unsigned o1 = (unsigned)__shfl_xor((int)min1A, d, 64);
        unsigned o2 = (unsigned)__shfl_xor((int)min2A, d, 64);
        asumA += __shfl_xor(asumA, d, 64);
        unsigned n1 = min1A < o1 ? min1A : o1;
        unsigned mx = min1A > o1 ? min1A : o1;
        unsigned mn = min2A < o2 ? min2A : o2;
        min2A = mn < mx ? mn : mx; min1A = n1;

        unsigned p1 = (unsigned)__shfl_xor((int)min1B, d, 64);
        unsigned p2 = (unsigned)__shfl_xor((int)min2B, d, 64);
        asumB += __shfl_xor(asumB, d, 64);
        unsigned m1 = min1B < p1 ? min1B : p1;
        unsigned my = min1B > p1 ? min1B : p1;
        unsigned mz = min2B < p2 ? min2B : p2;
        min2B = mz < my ? mz : my; min1B = m1;
    }

    float ssev = 0.f;
    if (q == 0) {   // row owner: lanes 0..15 -> 16+16 consecutive rows
        const int rowA = R0 + w * 32 + r16;
        const int rowB = rowA + 16;
        const unsigned bestA = min1A & 511u;
        const unsigned bestB = min1B & 511u;
        const float t1A = key2t(min1A), t2A = key2t(min2A);
        const float t1B = key2t(min1B), t2B = key2t(min2B);
        const bool flagA = (t2A < t1A + MARGIN_T);
        const bool flagB = (t2B < t1B + MARGIN_T);
        out[OFF_IDX + rowA] = (float)bestA;   // flagged rows corrected by fixup
        out[OFF_IDX + rowB] = (float)bestB;
        if (!flagA) { ssev += asumA + t1A; atomicAdd(&sHist[bestA], 1u); }
        else { unsigned s = atomicAdd(&sCnt, 1u); sFlagRows[s] = rowA; }
        if (!flagB) { ssev += asumB + t1B; atomicAdd(&sHist[bestB], 1u); }
        else { unsigned s = atomicAdd(&sCnt, 1u); sFlagRows[s] = rowB; }
    }
    // per-wave SSE reduce (owners hold nonzero), then block-level flush
#pragma unroll
    for (int off = 32; off; off >>= 1) ssev += __shfl_down(ssev, off);
    if (l == 0) sSseW[w] = (double)ssev;
    __syncthreads();

    if (tid == 0) sBase = atomicAdd(gCnt, sCnt);   // global list segment
    {   // flush histogram to partial hist (spreads atomic contention 64x)
        unsigned c = sHist[tid];
        if (c) atomicAdd(&gHistP[(blockIdx.x & (NPART - 1)) * KCODES + tid], c);
    }
    __syncthreads();
    if (tid < (int)sCnt) flagList[sBase + tid] = sFlagRows[tid];
    if (tid == 0) {
        double s = 0.0;
#pragma unroll
        for (int i = 0; i < 8; ++i) s += sSseW[i];
        atomicAdd(sseAcc, s);                 // one fp64 atomic per block (1024 total)
    }
}

// ---------- fixup: exact numpy-fp32 argmin over ALL 512 codes, listed rows ----------
// Grid-stride over the globally-compacted flag list, one 512-thread block per
// row, ONE CODE PER THREAD. The X row lives in REGISTERS: every xr index is
// COMPILE-TIME (full unroll) so SROA scalarizes the array (rule #20; round-6's
// partial unroll demoted xr to scratch: VGPR=44, 1.18 GB traffic).
// __launch_bounds__(512,2) (256-VGPR budget, ~150 used) avoids round-3's
// forced spill. X loads are wave-broadcast (same 256B line). Per-code fp64 fma
// order is bit-identical to numpy. u64-key reduce: wave shfl + LDS cross-wave,
// first-index tie-break. Contributes SSE (exact e) + histogram.

__global__ __launch_bounds__(512, 2) void vq_fixup(
    const float* __restrict__ X, const float* __restrict__ W,
    const float* __restrict__ Bsc, float* __restrict__ out,
    double* __restrict__ sseP, unsigned* __restrict__ gHistP,
    const int* __restrict__ flagList, const unsigned* __restrict__ gCnt) {
    __shared__ unsigned long long sKeyW[8];
    const unsigned total = *gCnt;
    const int t = threadIdx.x;               // == code id
    const int wv = t >> 6, l = t & 63;

    for (unsigned i = blockIdx.x; i < total; i += gridDim.x) {
        const int row = flagList[i];

        float xr[DIM];                       // SROA -> 64 VGPRs (static idx only)
        {
            const float4* Xr4 = (const float4*)(X + (size_t)row * DIM);
#pragma unroll
            for (int k4 = 0; k4 < 16; ++k4) {
                float4 v = Xr4[k4];
                xr[4 * k4 + 0] = v.x; xr[4 * k4 + 1] = v.y;
                xr[4 * k4 + 2] = v.z; xr[4 * k4 + 3] = v.w;
            }
        }
        const float A = np_sum_sq64(xr);     // numpy order, identical bits all threads

        // exact np_e for code t: fp64 dot in numpy's sequential order.
        // FULL unroll: all xr indices compile-time (rule #20).
        double acc = 0.0;
        {
            const float4* wr = (const float4*)(W + (size_t)t * DIM);
#pragma unroll
            for (int k4 = 0; k4 < 16; ++k4) {
                float4 f = wr[k4];
                acc = fma((double)f.x, (double)xr[4 * k4 + 0], acc);
                acc = fma((double)f.y, (double)xr[4 * k4 + 1], acc);
                acc = fma((double)f.z, (double)xr[4 * k4 + 2], acc);
                acc = fma((double)f.w, (double)xr[4 * k4 + 3], acc);
            }
        }
        unsigned long long bk;
        {
#pragma clang fp contract(off)
            float C2 = (float)(2.0 * acc);
            float e = (A + Bsc[t]) - C2;     // np fp32: (A+B) then subtract
            int iu = __float_as_int(e);
            unsigned u = ((unsigned)iu) ^ (((unsigned)(iu >> 31)) | 0x80000000u);
            bk = ((unsigned long long)u << 32) | (unsigned)t;
        }
#pragma unroll
        for (int d = 1; d < 64; d <<= 1) {
            unsigned long long o =
                (unsigned long long)__shfl_xor((long long)bk, d, 64);
            bk = bk < o ? bk : o;
        }
        if (l == 0) sKeyW[wv] = bk;
        __syncthreads();
        if (t == 0) {
            unsigned long long b = sKeyW[0];
#pragma unroll
            for (int k = 1; k < 8; ++k) if (sKeyW[k] < b) b = sKeyW[k];
            unsigned bestc = (unsigned)(b & 511ULL);
            unsigned u = (unsigned)(b >> 32);
            unsigned fb = (u & 0x80000000u) ? (u & 0x7FFFFFFFu) : ~u;
            float ebest = __uint_as_float(fb);   // exact np-fp32 e of the winner
            out[OFF_IDX + row] = (float)bestc;
            atomicAdd(&gHistP[(i & (NPART - 1)) * KCODES + bestc], 1u);
            atomicAdd(&sseP[i & (NPART - 1)], (double)ebest);   // SSE = e
        }
        __syncthreads();                     // protect sKeyW before next iter
    }
}

// ---------- scatter: pure gather W[best] -> Q (no atomics, no X read) ----------
// One wave per row. Index load is wave-uniform, W gather is one coalesced
// 256B read (L2-hot), store coalesced. Runs on FINAL indices (post-fixup).

__global__ __launch_bounds__(256) void vq_scatter(
    const float* __restrict__ W, float* __restrict__ out) {
    const int gid = blockIdx.x * 256 + threadIdx.x;
    const int row = gid >> 6;
    const int lane = gid & 63;
    int idx = (int)out[OFF_IDX + row];
    if ((unsigned)idx >= KCODES) idx = KCODES - 1;   // safety clamp
    out[OFF_Q + (size_t)row * DIM + lane] = W[(size_t)idx * DIM + lane];
}

// ---------- finalize: sum partial hists -> perplexity; sse -> loss ----------

__global__ __launch_bounds__(512) void vq_finalize(
    const double* __restrict__ sseAcc, const double* __restrict__ sseP,
    const unsigned* __restrict__ gHistP, float* __restrict__ out) {
    __shared__ float partial[8];
    const int t = threadIdx.x;
    unsigned c = 0;
#pragma unroll 8
    for (int p = 0; p < NPART; ++p) c += gHistP[p * KCODES + t];
    float pf = (float)c * (1.0f / (float)N_ROWS);
    float v = pf * logf(pf + 1e-10f);
#pragma unroll
    for (int off = 32; off; off >>= 1) v += __shfl_down(v, off);
    if ((t & 63) == 0) partial[t >> 6] = v;
    __syncthreads();
    if (t == 0) {
        float s = 0.f;
#pragma unroll
        for (int i = 0; i < 8; ++i) s += partial[i];
        out[OFF_PERP] = expf(-s) * (1.0f / (float)KCODES);
        double s2 = sseAcc[0];
#pragma unroll
        for (int i = 0; i < NPART; ++i) s2 += sseP[i];
        out[0] = (float)(1.25 * s2 * (1.0 / ((double)N_ROWS * (double)DIM)));
    }
}

extern "C" void kernel_launch(void* const* d_in, const int* in_sizes, int n_in,
                              void* d_out, int out_size, void* d_ws, size_t ws_size,
                              hipStream_t stream) {
    const float* X = (const float*)d_in[0];
    const float* W = (const float*)d_in[1];
    float* out = (float*)d_out;
    double* sseAcc = (double*)d_ws;
    double* sseP = (double*)((char*)d_ws + 64);       // 64 slots
    unsigned* gCnt = (unsigned*)((char*)d_ws + 64 + NPART * sizeof(double));

    size_t zb = 64 + NPART * sizeof(double) + 64;     // 640 B of ws used
    if (zb > ws_size) zb = ws_size;
    hipMemsetAsync(d_ws, 0, zb, stream);

    // Scratch lives in the quantized region of `out` (dead until vq_scatter,
    // which runs LAST, overwrites it). 16B-align the base so uint4/float4
    // staging loads are aligned. Layout: WhiG | WloG | Bsc | gHistP | flagList.
    uintptr_t sbase = ((uintptr_t)(out + OFF_Q) + 15) & ~(uintptr_t)15;
    unsigned short* WhiG = (unsigned short*)sbase;                // 64 KiB
    unsigned short* WloG = WhiG + (size_t)KCODES * DIM;           // 64 KiB
    float* Bsc = (float*)(WloG + (size_t)KCODES * DIM);           // 2 KiB
    unsigned* gHistP = (unsigned*)(Bsc + KCODES);                 // 128 KiB
    int* flagList = (int*)(gHistP + (size_t)NPART * KCODES);      // <=1 MiB
    hipMemsetAsync(gHistP, 0, (size_t)NPART * KCODES * sizeof(unsigned), stream);

    vq_prep<<<2, 256, 0, stream>>>(W, WhiG, WloG, Bsc);
    vq_argmin<<<NBLOCKS, THREADS, 0, stream>>>(X, WhiG, WloG, Bsc, out,
                                               sseAcc, gHistP, flagList, gCnt);
    vq_fixup<<<NBLOCKS, 512, 0, stream>>>(X, W, Bsc, out, sseP, gHistP,
                                          flagList, gCnt);
    vq_finalize<<<1, 512, 0, stream>>>(sseAcc, sseP, gHistP, out);
    vq_scatter<<<(N_ROWS * DIM) / 256, 256, 0, stream>>>(W, out);
}